// Round 8
// baseline (228.980 us; speedup 1.0000x reference)
//
#include <hip/hip_runtime.h>

namespace {

constexpr int T_LEN = 512;
constexpr int XS    = 516;   // padded floats per x-row in LDS

typedef _Float16 half8  __attribute__((ext_vector_type(8)));
typedef float    f32x4v __attribute__((ext_vector_type(4)));
typedef unsigned uint2v __attribute__((ext_vector_type(2)));
typedef unsigned uint4v __attribute__((ext_vector_type(4)));

#define MFMA32(a, b, c) __builtin_amdgcn_mfma_f32_16x16x32_f16((a), (b), (c), 0, 0, 0)

// tanh(y) = 1 - 2/(2^(SCL*y)+1) with SCL = 2*log2(e) pre-folded into weights.
constexpr float SCL = 2.8853900817779268f;

__device__ __forceinline__ float exp2_fast(float x) {
#if __has_builtin(__builtin_amdgcn_exp2f)
    return __builtin_amdgcn_exp2f(x);
#else
    return exp2f(x);
#endif
}

// Load an fp16 A-fragment from a row-major 64x64 fp32 matrix, scaled.
__device__ __forceinline__ half8 load_frag(const float* __restrict__ W,
                                           int row, int k0, float s) {
    const float* p = W + row * 64 + k0;
    f32x4v lo = *reinterpret_cast<const f32x4v*>(p);
    f32x4v hi = *reinterpret_cast<const f32x4v*>(p + 4);
    uint4v u;
    u.x = __builtin_bit_cast(unsigned, __builtin_amdgcn_cvt_pkrtz(lo.x * s, lo.y * s));
    u.y = __builtin_bit_cast(unsigned, __builtin_amdgcn_cvt_pkrtz(lo.z * s, lo.w * s));
    u.z = __builtin_bit_cast(unsigned, __builtin_amdgcn_cvt_pkrtz(hi.x * s, hi.y * s));
    u.w = __builtin_bit_cast(unsigned, __builtin_amdgcn_cvt_pkrtz(hi.z * s, hi.w * s));
    return __builtin_bit_cast(half8, u);
}

// a holds SCL*preact (log2-domain); robust at +-inf.
__device__ __forceinline__ void tanh4(f32x4v &a) {
#pragma unroll
    for (int q = 0; q < 4; ++q) {
        float e = exp2_fast(a[q]);
        a[q] = 1.0f - 2.0f * __builtin_amdgcn_rcpf(e + 1.0f);
    }
}

// Swizzled halves-offset into a [16][64]-half exchange buffer.
__device__ __forceinline__ int swz_off(int b, int ro) {
    const int chunk = ro >> 3;
    const int within = ro & 7;
    return (b << 6) + ((chunk ^ (b & 7)) << 3) + within;
}

__global__ __launch_bounds__(512, 1)
void rnn_hh_kernel(const float* __restrict__ x,
                   const float* __restrict__ Wih0,
                   const float* __restrict__ Whh0,
                   const float* __restrict__ bih0,
                   const float* __restrict__ bhh0,
                   const float* __restrict__ Wih1,
                   const float* __restrict__ Whh1,
                   const float* __restrict__ bih1,
                   const float* __restrict__ bhh1,
                   const float* __restrict__ fc1W,
                   const float* __restrict__ fc1b,
                   const float* __restrict__ fc2W,
                   const float* __restrict__ fc2b,
                   float* __restrict__ out)
{
    const int tid    = threadIdx.x;        // 512 threads = 8 waves
    const int w      = tid >> 6;
    const int q      = w & 3;              // row-quarter: rows 16q..16q+15
    const int hh     = w >> 2;             // batch half this wave finishes
    const int lane   = tid & 63;
    const int g      = lane >> 4;
    const int b16    = lane & 15;          // batch column
    const bool own   = ((b16 >> 3) == hh); // lane's column is in this wave's half
    const int batch0 = blockIdx.x * 16;

    __shared__ float    sx[16 * XS];       // whole x tile, staged once
    __shared__ _Float16 sh1[2][16 * 64];   // h1 exchange, ping-pong, swizzled
    __shared__ _Float16 sh2[2][16 * 64];   // h2 exchange
    __shared__ float    pf[4][16];         // fc2 partials

    // ---- stage x[batch0..+15][0..511] into LDS (coalesced f32x4) ----
    {
        const float* gx = x + (size_t)batch0 * T_LEN;
#pragma unroll
        for (int c = 0; c < 4; ++c) {
            int idx = tid + c * 512;            // float4 index 0..2047
            int r = idx >> 7, c4 = idx & 127;
            f32x4v v = *reinterpret_cast<const f32x4v*>(gx + r * T_LEN + c4 * 4);
            *reinterpret_cast<f32x4v*>(&sx[r * XS + c4 * 4]) = v;
        }
    }

    // ---- per-wave persistent weights (SCL folds tanh's 2y and log2e) ----
    const int row = 16 * q + b16;
    const int ro  = 16 * q + 4 * g;

    const half8 WA0_0 = load_frag(Whh0, row,      8 * g, SCL);
    const half8 WA0_1 = load_frag(Whh0, row, 32 + 8 * g, SCL);
    const half8 WI1_0 = load_frag(Wih1, row,      8 * g, SCL);
    const half8 WI1_1 = load_frag(Wih1, row, 32 + 8 * g, SCL);
    const half8 WH1_0 = load_frag(Whh1, row,      8 * g, SCL);
    const half8 WH1_1 = load_frag(Whh1, row, 32 + 8 * g, SCL);

    f32x4v bb0, bb1, wx2;
#pragma unroll
    for (int iq = 0; iq < 4; ++iq) {
        const int o = 16 * q + 4 * g + iq;
        bb0[iq] = SCL * (bih0[o] + bhh0[o]);
        bb1[iq] = SCL * (bih1[o] + bhh1[o]);
        wx2[iq] = SCL * Wih0[o];
    }

    // step-invariant LDS offsets (halves)
    const int wr_off = swz_off(b16, ro);
    const int rd_b0  = swz_off(b16, 8 * g);
    const int rd_b1  = swz_off(b16, 32 + 8 * g);

    auto publish = [&](_Float16* base, const f32x4v& a) {
        uint2v p;
        p.x = __builtin_bit_cast(unsigned, __builtin_amdgcn_cvt_pkrtz(a[0], a[1]));
        p.y = __builtin_bit_cast(unsigned, __builtin_amdgcn_cvt_pkrtz(a[2], a[3]));
        *reinterpret_cast<uint2v*>(base + wr_off) = p;
    };

    half8 Bh1_0 = {}, Bh1_1 = {}, Bh2_0 = {}, Bh2_1 = {};

    __syncthreads();                       // x staged

    float xt = sx[b16 * XS + 0];
    float xn = sx[b16 * XS + 1];

    // ---- peel k=0: h1(0) = tanh(wx*x0 + b0); h2(-1) = 0 ----
    {
        f32x4v a0 = wx2 * xt + bb0;
        if (own) {
            tanh4(a0);
            publish(sh1[0], a0);
            *reinterpret_cast<uint2v*>(&sh2[0][0] + wr_off) = uint2v{0, 0};
        }
        __syncthreads();
        if (own) {
            Bh1_0 = *reinterpret_cast<const half8*>(&sh1[0][0] + rd_b0);
            Bh1_1 = *reinterpret_cast<const half8*>(&sh1[0][0] + rd_b1);
            Bh2_0 = *reinterpret_cast<const half8*>(&sh2[0][0] + rd_b0);
            Bh2_1 = *reinterpret_cast<const half8*>(&sh2[0][0] + rd_b1);
        }
        xt = xn; xn = sx[b16 * XS + 2];
    }

    // ---- main: iter k computes h1(k) and h2(k-1); one barrier per step ----
#pragma unroll 2
    for (int k = 1; k < T_LEN; ++k) {
        const int s = k & 1;
        const float xf = sx[b16 * XS + k + 2];   // prefetch (pad covers k=511)

        f32x4v zz = {};
        // 6 MFMAs (full 16 cols; foreign-half cols are garbage, discarded)
        f32x4v u0 = MFMA32(WA0_0, Bh1_0, wx2 * xt + bb0);
        f32x4v v0 = MFMA32(WA0_1, Bh1_1, zz);
        f32x4v u1 = MFMA32(WI1_0, Bh1_0, bb1);
        f32x4v v1 = MFMA32(WH1_0, Bh2_0, zz);
        u1 = MFMA32(WI1_1, Bh1_1, u1);
        v1 = MFMA32(WH1_1, Bh2_1, v1);

        if (own) {
            f32x4v a0 = u0 + v0;
            tanh4(a0);                       // 32 active lanes: half-cost trans
            publish(sh1[s], a0);             // h1(k)
            f32x4v a1 = u1 + v1;
            tanh4(a1);
            publish(sh2[s], a1);             // h2(k-1)
        }
        __syncthreads();
        if (own) {
            Bh1_0 = *reinterpret_cast<const half8*>(&sh1[s][0] + rd_b0);
            Bh1_1 = *reinterpret_cast<const half8*>(&sh1[s][0] + rd_b1);
            Bh2_0 = *reinterpret_cast<const half8*>(&sh2[s][0] + rd_b0);
            Bh2_1 = *reinterpret_cast<const half8*>(&sh2[s][0] + rd_b1);
        }
        xt = xn; xn = xf;
    }

    // ---- epilogue: h2(511) from h1(511), h2(510) ----
    {
        f32x4v zz = {};
        f32x4v u1 = MFMA32(WI1_0, Bh1_0, bb1);
        f32x4v v1 = MFMA32(WH1_0, Bh2_0, zz);
        u1 = MFMA32(WI1_1, Bh1_1, u1);
        v1 = MFMA32(WH1_1, Bh2_1, v1);
        if (own) {
            f32x4v a1 = u1 + v1;
            tanh4(a1);
            publish(sh2[0], a1);
        }
        __syncthreads();
    }

    // ---- fc1 + relu + fc2 (waves hh==0; fresh full-width reads) ----
    if (hh == 0) {
        half8 E0 = *reinterpret_cast<const half8*>(&sh2[0][0] + rd_b0);
        half8 E1 = *reinterpret_cast<const half8*>(&sh2[0][0] + rd_b1);
        const half8 F0 = load_frag(fc1W, row,      8 * g, 1.0f);
        const half8 F1 = load_frag(fc1W, row, 32 + 8 * g, 1.0f);
        f32x4v zf;
#pragma unroll
        for (int iq = 0; iq < 4; ++iq) zf[iq] = fc1b[16 * q + 4 * g + iq];
        zf = MFMA32(F0, E0, zf);
        zf = MFMA32(F1, E1, zf);

        float pacc = 0.0f;
#pragma unroll
        for (int iq = 0; iq < 4; ++iq)
            pacc += fmaxf(zf[iq], 0.0f) * fc2W[16 * q + 4 * g + iq];
        pacc += __shfl_xor(pacc, 16);
        pacc += __shfl_xor(pacc, 32);
        if (lane < 16) pf[q][lane] = pacc;
    }
    __syncthreads();
    if (tid < 16)
        out[batch0 + tid] = pf[0][tid] + pf[1][tid] + pf[2][tid] + pf[3][tid]
                          + fc2b[0];
}

} // namespace

extern "C" void kernel_launch(void* const* d_in, const int* in_sizes, int n_in,
                              void* d_out, int out_size, void* d_ws, size_t ws_size,
                              hipStream_t stream) {
    (void)n_in; (void)out_size; (void)d_ws; (void)ws_size;
    const float* x    = (const float*)d_in[0];
    const float* Wih0 = (const float*)d_in[1];
    const float* Whh0 = (const float*)d_in[2];
    const float* bih0 = (const float*)d_in[3];
    const float* bhh0 = (const float*)d_in[4];
    const float* Wih1 = (const float*)d_in[5];
    const float* Whh1 = (const float*)d_in[6];
    const float* bih1 = (const float*)d_in[7];
    const float* bhh1 = (const float*)d_in[8];
    const float* fc1W = (const float*)d_in[9];
    const float* fc1b = (const float*)d_in[10];
    const float* fc2W = (const float*)d_in[11];
    const float* fc2b = (const float*)d_in[12];
    float* out = (float*)d_out;

    const int B = in_sizes[0] / T_LEN;      // 4096
    dim3 grid(B / 16), block(512);
    rnn_hh_kernel<<<grid, block, 0, stream>>>(
        x, Wih0, Whh0, bih0, bhh0, Wih1, Whh1, bih1, bhh1,
        fc1W, fc1b, fc2W, fc2b, out);
}

// Round 9
// 126.641 us; speedup vs baseline: 1.8081x; 1.8081x over previous
//
#include <hip/hip_runtime.h>

namespace {

constexpr int T_LEN = 512;
constexpr int XS    = 516;   // padded floats per x-row in LDS

typedef _Float16 half8  __attribute__((ext_vector_type(8)));
typedef float    f32x4v __attribute__((ext_vector_type(4)));
typedef unsigned uint2v __attribute__((ext_vector_type(2)));
typedef unsigned uint4v __attribute__((ext_vector_type(4)));

#define MFMA32(a, b, c) __builtin_amdgcn_mfma_f32_16x16x32_f16((a), (b), (c), 0, 0, 0)

// tanh(y) = 1 - 2/(2^(SCL*y)+1) with SCL = 2*log2(e) pre-folded into weights.
constexpr float SCL = 2.8853900817779268f;

__device__ __forceinline__ float exp2_fast(float x) {
#if __has_builtin(__builtin_amdgcn_exp2f)
    return __builtin_amdgcn_exp2f(x);
#else
    return exp2f(x);
#endif
}

// Load an fp16 A-fragment from a row-major 64x64 fp32 matrix, scaled.
__device__ __forceinline__ half8 load_frag(const float* __restrict__ W,
                                           int row, int k0, float s) {
    const float* p = W + row * 64 + k0;
    f32x4v lo = *reinterpret_cast<const f32x4v*>(p);
    f32x4v hi = *reinterpret_cast<const f32x4v*>(p + 4);
    uint4v u;
    u.x = __builtin_bit_cast(unsigned, __builtin_amdgcn_cvt_pkrtz(lo.x * s, lo.y * s));
    u.y = __builtin_bit_cast(unsigned, __builtin_amdgcn_cvt_pkrtz(lo.z * s, lo.w * s));
    u.z = __builtin_bit_cast(unsigned, __builtin_amdgcn_cvt_pkrtz(hi.x * s, hi.y * s));
    u.w = __builtin_bit_cast(unsigned, __builtin_amdgcn_cvt_pkrtz(hi.z * s, hi.w * s));
    return __builtin_bit_cast(half8, u);
}

// Fused dual tanh: a0,a1 hold SCL*preact (log2-domain). Batches all 8 exp2,
// then 8 adds, then 8 rcp, then 8 fma -> trans pipe runs back-to-back.
__device__ __forceinline__ void tanh8(f32x4v &a0, f32x4v &a1) {
    float e[8];
#pragma unroll
    for (int q = 0; q < 4; ++q) e[q]     = exp2_fast(a0[q]);
#pragma unroll
    for (int q = 0; q < 4; ++q) e[4 + q] = exp2_fast(a1[q]);
#pragma unroll
    for (int q = 0; q < 8; ++q) e[q] += 1.0f;
#pragma unroll
    for (int q = 0; q < 4; ++q) a0[q] = 1.0f - 2.0f * __builtin_amdgcn_rcpf(e[q]);
#pragma unroll
    for (int q = 0; q < 4; ++q) a1[q] = 1.0f - 2.0f * __builtin_amdgcn_rcpf(e[4 + q]);
}

// Swizzled halves-offset into a [16][64]-half exchange buffer.
__device__ __forceinline__ int swz_off(int b, int ro) {
    const int chunk = ro >> 3;
    const int within = ro & 7;
    return (b << 6) + ((chunk ^ (b & 7)) << 3) + within;
}

__global__ __launch_bounds__(256, 2)
void rnn_tuned_kernel(const float* __restrict__ x,
                      const float* __restrict__ Wih0,
                      const float* __restrict__ Whh0,
                      const float* __restrict__ bih0,
                      const float* __restrict__ bhh0,
                      const float* __restrict__ Wih1,
                      const float* __restrict__ Whh1,
                      const float* __restrict__ bih1,
                      const float* __restrict__ bhh1,
                      const float* __restrict__ fc1W,
                      const float* __restrict__ fc1b,
                      const float* __restrict__ fc2W,
                      const float* __restrict__ fc2b,
                      float* __restrict__ out)
{
    const int tid    = threadIdx.x;        // 256 threads = 4 waves
    const int wv     = tid >> 6;           // wave owns hidden rows 16wv..16wv+15
    const int lane   = tid & 63;
    const int g      = lane >> 4;
    const int b16    = lane & 15;          // batch within 16-batch tile
    const int batch0 = blockIdx.x * 16;

    __shared__ float    sx[16 * XS];       // whole x tile, staged once
    __shared__ _Float16 sh1[2][16 * 64];   // h1 exchange, ping-pong, swizzled
    __shared__ _Float16 sh2[2][16 * 64];   // h2 exchange
    __shared__ float    pf[4][16];         // fc2 partials

    // ---- stage x[batch0..+15][0..511] into LDS (coalesced f32x4) ----
    {
        const float* gx = x + (size_t)batch0 * T_LEN;
#pragma unroll
        for (int c = 0; c < 8; ++c) {
            int idx = tid + c * 256;            // float4 index 0..2047
            int r = idx >> 7, c4 = idx & 127;   // 128 float4 per row
            f32x4v v = *reinterpret_cast<const f32x4v*>(gx + r * T_LEN + c4 * 4);
            *reinterpret_cast<f32x4v*>(&sx[r * XS + c4 * 4]) = v;
        }
    }

    // ---- per-wave persistent weights (SCL folds tanh's 2y and log2e) ----
    const int row = 16 * wv + b16;
    const int ro  = 16 * wv + 4 * g;

    const half8 WA0_0 = load_frag(Whh0, row,      8 * g, SCL);
    const half8 WA0_1 = load_frag(Whh0, row, 32 + 8 * g, SCL);
    const half8 WI1_0 = load_frag(Wih1, row,      8 * g, SCL);
    const half8 WI1_1 = load_frag(Wih1, row, 32 + 8 * g, SCL);
    const half8 WH1_0 = load_frag(Whh1, row,      8 * g, SCL);
    const half8 WH1_1 = load_frag(Whh1, row, 32 + 8 * g, SCL);

    f32x4v bb0, bb1, wx2;
#pragma unroll
    for (int q = 0; q < 4; ++q) {
        const int o = 16 * wv + 4 * g + q;
        bb0[q] = SCL * (bih0[o] + bhh0[o]);
        bb1[q] = SCL * (bih1[o] + bhh1[o]);
        wx2[q] = SCL * Wih0[o];
    }

    // step-invariant LDS offsets (halves)
    const int wr_off = swz_off(b16, ro);
    const int rd_b0  = swz_off(b16, 8 * g);
    const int rd_b1  = swz_off(b16, 32 + 8 * g);

    auto publish = [&](_Float16* base, const f32x4v& a) {
        uint2v p;
        p.x = __builtin_bit_cast(unsigned, __builtin_amdgcn_cvt_pkrtz(a[0], a[1]));
        p.y = __builtin_bit_cast(unsigned, __builtin_amdgcn_cvt_pkrtz(a[2], a[3]));
        *reinterpret_cast<uint2v*>(base + wr_off) = p;
    };

    half8 Bh1_0, Bh1_1, Bh2_0, Bh2_1;

    __syncthreads();                       // x staged

    float xt = sx[b16 * XS + 0];
    float xn = sx[b16 * XS + 1];

    // ---- peel k=0: h1(0) = tanh(wx*x0 + b0); h2(-1) = 0 ----
    {
        f32x4v a0 = wx2 * xt + bb0;
#pragma unroll
        for (int q = 0; q < 4; ++q) {
            float e = exp2_fast(a0[q]);
            a0[q] = 1.0f - 2.0f * __builtin_amdgcn_rcpf(e + 1.0f);
        }
        publish(sh1[0], a0);
        *reinterpret_cast<uint2v*>(&sh2[0][0] + wr_off) = uint2v{0, 0};
        __syncthreads();
        // h2 frags first (feed the 2-deep chain), then h1
        Bh2_0 = *reinterpret_cast<const half8*>(&sh2[0][0] + rd_b0);
        Bh2_1 = *reinterpret_cast<const half8*>(&sh2[0][0] + rd_b1);
        Bh1_0 = *reinterpret_cast<const half8*>(&sh1[0][0] + rd_b0);
        Bh1_1 = *reinterpret_cast<const half8*>(&sh1[0][0] + rd_b1);
        xt = xn; xn = sx[b16 * XS + 2];
    }

    // ---- main: iter k computes h1(k) and h2(k-1); one barrier per step ----
#pragma unroll 2
    for (int k = 1; k < T_LEN; ++k) {
        const int s = k & 1;
        const float xf = sx[b16 * XS + k + 2];   // prefetch (pad covers k=511)

        f32x4v zz = {};
        // v1 2-deep chain first (longest), on the first-needed Bh2 frags
        f32x4v v1 = MFMA32(WH1_0, Bh2_0, bb1);
        f32x4v u1 = MFMA32(WI1_0, Bh1_0, zz);
        f32x4v u0 = MFMA32(WA0_0, Bh1_0, wx2 * xt + bb0);
        f32x4v v0 = MFMA32(WA0_1, Bh1_1, zz);
        v1 = MFMA32(WH1_1, Bh2_1, v1);
        u1 = MFMA32(WI1_1, Bh1_1, u1);

        f32x4v a0 = u0 + v0;
        f32x4v a1 = u1 + v1;
        tanh8(a0, a1);                           // fused trans burst
        publish(sh1[s], a0);                     // h1(k)
        publish(sh2[s], a1);                     // h2(k-1)

        __syncthreads();
        Bh2_0 = *reinterpret_cast<const half8*>(&sh2[s][0] + rd_b0);
        Bh2_1 = *reinterpret_cast<const half8*>(&sh2[s][0] + rd_b1);
        Bh1_0 = *reinterpret_cast<const half8*>(&sh1[s][0] + rd_b0);
        Bh1_1 = *reinterpret_cast<const half8*>(&sh1[s][0] + rd_b1);
        xt = xn; xn = xf;
    }

    // ---- epilogue: h2(511) from h1(511), h2(510) ----
    {
        f32x4v zz = {};
        f32x4v v1 = MFMA32(WH1_0, Bh2_0, bb1);
        f32x4v u1 = MFMA32(WI1_0, Bh1_0, zz);
        v1 = MFMA32(WH1_1, Bh2_1, v1);
        u1 = MFMA32(WI1_1, Bh1_1, u1);
        f32x4v a1 = u1 + v1;
#pragma unroll
        for (int q = 0; q < 4; ++q) {
            float e = exp2_fast(a1[q]);
            a1[q] = 1.0f - 2.0f * __builtin_amdgcn_rcpf(e + 1.0f);
        }
        publish(sh2[0], a1);
        __syncthreads();
        Bh2_0 = *reinterpret_cast<const half8*>(&sh2[0][0] + rd_b0);
        Bh2_1 = *reinterpret_cast<const half8*>(&sh2[0][0] + rd_b1);
    }

    // ---- fc1 + relu + fc2 ----
    {
        const half8 F0 = load_frag(fc1W, row,      8 * g, 1.0f);
        const half8 F1 = load_frag(fc1W, row, 32 + 8 * g, 1.0f);
        f32x4v zf;
#pragma unroll
        for (int q = 0; q < 4; ++q) zf[q] = fc1b[16 * wv + 4 * g + q];
        zf = MFMA32(F0, Bh2_0, zf);
        zf = MFMA32(F1, Bh2_1, zf);

        float pacc = 0.0f;
#pragma unroll
        for (int q = 0; q < 4; ++q)
            pacc += fmaxf(zf[q], 0.0f) * fc2W[16 * wv + 4 * g + q];
        pacc += __shfl_xor(pacc, 16);
        pacc += __shfl_xor(pacc, 32);
        if (lane < 16) pf[wv][lane] = pacc;
    }
    __syncthreads();
    if (tid < 16)
        out[batch0 + tid] = pf[0][tid] + pf[1][tid] + pf[2][tid] + pf[3][tid]
                          + fc2b[0];
}

} // namespace

extern "C" void kernel_launch(void* const* d_in, const int* in_sizes, int n_in,
                              void* d_out, int out_size, void* d_ws, size_t ws_size,
                              hipStream_t stream) {
    (void)n_in; (void)out_size; (void)d_ws; (void)ws_size;
    const float* x    = (const float*)d_in[0];
    const float* Wih0 = (const float*)d_in[1];
    const float* Whh0 = (const float*)d_in[2];
    const float* bih0 = (const float*)d_in[3];
    const float* bhh0 = (const float*)d_in[4];
    const float* Wih1 = (const float*)d_in[5];
    const float* Whh1 = (const float*)d_in[6];
    const float* bih1 = (const float*)d_in[7];
    const float* bhh1 = (const float*)d_in[8];
    const float* fc1W = (const float*)d_in[9];
    const float* fc1b = (const float*)d_in[10];
    const float* fc2W = (const float*)d_in[11];
    const float* fc2b = (const float*)d_in[12];
    float* out = (float*)d_out;

    const int B = in_sizes[0] / T_LEN;      // 4096
    dim3 grid(B / 16), block(256);
    rnn_tuned_kernel<<<grid, block, 0, stream>>>(
        x, Wih0, Whh0, bih0, bhh0, Wih1, Whh1, bih1, bhh1,
        fc1W, fc1b, fc2W, fc2b, out);
}